// Round 3
// baseline (33.091 us; speedup 1.0000x reference)
//
#include <hip/hip_runtime.h>
#include <math.h>

#define WPB 4

__device__ __forceinline__ void gld16(const float* g, void* l) {
    // async global->LDS, 16B per lane: lds[base + lane*16] <- g[lane address]
    __builtin_amdgcn_global_load_lds((const __attribute__((address_space(1))) void*)g,
                                     (__attribute__((address_space(3))) void*)l, 16, 0, 0);
}

// Fast path: D==16, R==8, I==512.
// One block (4 waves) per batch row b; the 8 pairs of b are 8 tiles.
// Tile = one pair's 16 W rows (32KB) staged to LDS, double-buffered via
// global_load_lds. Wave w owns rows 4w..4w+3 (stages AND computes them), so
// the main loop has no barriers — only counted s_waitcnt vmcnt(8) (tile t+1's
// 8 loads stay in flight while computing tile t).
__global__ __launch_bounds__(256)
void huff_lds16(const float* __restrict__ x, const int* __restrict__ tgt,
                const float* __restrict__ W, const float* __restrict__ bias,
                const int* __restrict__ paths, const float* __restrict__ codes,
                float* __restrict__ out)
{
    __shared__ float4 wbuf[2][16][128];   // 64 KB double-buffered W tile
    __shared__ float4 xbuf[128];          // 2 KB x row
    __shared__ float  qbuf[8][4];         // per-(pair,wave) partial products

    const int lane = threadIdx.x & 63;
    const int w    = threadIdx.x >> 6;
    const int b    = blockIdx.x;
    const int p0   = b * 8;

    // Metadata: lane d (0..15) holds node id / sign / bias for path entry d.
    const int dd = lane & 15;
    int nd[8]; float sd[8], bv[8];
    #pragma unroll
    for (int p = 0; p < 8; ++p) {
        const int c = tgt[p0 + p];
        nd[p] = paths[(size_t)c * 16 + dd];
        const float cd = codes[(size_t)c * 16 + dd];
        sd[p] = 1.0f - 2.0f * cd;
        bv[p] = bias[nd[p]];
    }

    // Drain compiler-issued loads so manual vmcnt counting is exact.
    asm volatile("s_waitcnt vmcnt(0)" ::: "memory");

    // Prologue: wave 0 stages x (2 instr); every wave stages its tile-0 rows (8 instr).
    if (w == 0) {
        const float* xs = x + (size_t)b * 512 + lane * 4;
        gld16(xs,       (float*)xbuf);
        gld16(xs + 256, (float*)xbuf + 256);
    }
    #pragma unroll
    for (int k = 0; k < 4; ++k) {
        const int r = 4 * w + k;
        const int node = __shfl(nd[0], r);
        const float* src = W + (size_t)node * 512 + lane * 4;
        gld16(src,       &wbuf[0][r][0]);
        gld16(src + 256, (float*)&wbuf[0][r][0] + 256);
    }
    if (w == 0) { asm volatile("s_waitcnt vmcnt(8)" ::: "memory"); } // x landed
    __builtin_amdgcn_s_barrier();                                    // x visible to all
    asm volatile("" ::: "memory");

    const float4 xa = xbuf[lane];        // x held in registers for all 8 tiles
    const float4 xc = xbuf[lane + 64];

    #pragma unroll
    for (int t = 0; t < 8; ++t) {
        if (t < 7) {  // stage tile t+1 into the other buffer (wave-own rows)
            #pragma unroll
            for (int k = 0; k < 4; ++k) {
                const int r = 4 * w + k;
                const int node = __shfl(nd[t + 1], r);
                const float* src = W + (size_t)node * 512 + lane * 4;
                gld16(src,       &wbuf[(t + 1) & 1][r][0]);
                gld16(src + 256, (float*)&wbuf[(t + 1) & 1][r][0] + 256);
            }
            asm volatile("s_waitcnt vmcnt(8)" ::: "memory"); // tile t done, t+1 in flight
        } else {
            asm volatile("s_waitcnt vmcnt(0)" ::: "memory"); // last tile: drain
        }

        float acc[4];
        #pragma unroll
        for (int k = 0; k < 4; ++k) {
            const float4 wa = wbuf[t & 1][4 * w + k][lane];
            const float4 wb = wbuf[t & 1][4 * w + k][lane + 64];
            acc[k] = xa.x * wa.x + xa.y * wa.y + xa.z * wa.z + xa.w * wa.w
                   + xc.x * wb.x + xc.y * wb.y + xc.z * wb.z + xc.w * wb.w;
        }
        #pragma unroll
        for (int off = 32; off; off >>= 1) {
            #pragma unroll
            for (int k = 0; k < 4; ++k)
                acc[k] += __shfl_xor(acc[k], off, 64);
        }

        float qw = 1.0f;
        #pragma unroll
        for (int k = 0; k < 4; ++k) {
            const float tt = acc[k] + __shfl(bv[t], 4 * w + k);
            const float s  = __shfl(sd[t], 4 * w + k);
            qw *= 1.0f + __expf(-s * tt);   // prod sigmoid = 1/prod(1+exp(-s*t))
        }
        if (lane == 0) qbuf[t][w] = qw;
    }

    __syncthreads();
    if (threadIdx.x < 8) {
        const float q = qbuf[threadIdx.x][0] * qbuf[threadIdx.x][1]
                      * qbuf[threadIdx.x][2] * qbuf[threadIdx.x][3];
        out[p0 + threadIdx.x] = 1.0f / q;
    }
}

// Generic fallback (round-2 structure, correct for any shape).
__global__ __launch_bounds__(WPB * 64)
void huff_kernel_gen(const float* __restrict__ x, const int* __restrict__ tgt,
                     const float* __restrict__ W, const float* __restrict__ bias,
                     const int* __restrict__ paths, const float* __restrict__ codes,
                     float* __restrict__ out, int R, int I, int D, int npairs)
{
    const int lane = threadIdx.x & 63;
    const int p = blockIdx.x * WPB + (threadIdx.x >> 6);
    if (p >= npairs) return;
    const int b = p / R;
    const float4* xrow = reinterpret_cast<const float4*>(x + (size_t)b * I);
    const float4 xa = xrow[lane];
    const float4 xb = xrow[lane + 64];
    const int c = tgt[p];
    float q = 1.0f;
    for (int d = 0; d < D; ++d) {
        const int node = paths[(size_t)c * D + d];
        const float4* wr = reinterpret_cast<const float4*>(W + (size_t)node * I);
        const float4 wa = wr[lane];
        const float4 wb = wr[lane + 64];
        float acc = xa.x * wa.x + xa.y * wa.y + xa.z * wa.z + xa.w * wa.w
                  + xb.x * wb.x + xb.y * wb.y + xb.z * wb.z + xb.w * wb.w;
        #pragma unroll
        for (int off = 32; off; off >>= 1) acc += __shfl_xor(acc, off, 64);
        const float t = acc + bias[node];
        const float s = 1.0f - 2.0f * codes[(size_t)c * D + d];
        q *= 1.0f + __expf(-s * t);
    }
    if (lane == 0) out[p] = 1.0f / q;
}

extern "C" void kernel_launch(void* const* d_in, const int* in_sizes, int n_in,
                              void* d_out, int out_size, void* d_ws, size_t ws_size,
                              hipStream_t stream) {
    const float* x     = (const float*)d_in[0];
    const int*   tgt   = (const int*)  d_in[1];
    const float* W     = (const float*)d_in[2];
    const float* bias  = (const float*)d_in[3];
    const int*   paths = (const int*)  d_in[4];
    const float* codes = (const float*)d_in[5];
    float* out = (float*)d_out;

    const int N = in_sizes[3];            // total_nodes = nb_classes - 1
    const int C = N + 1;                  // nb_classes
    const int I = in_sizes[2] / N;        // input dim (512)
    const int B = in_sizes[0] / I;        // batch (1024)
    const int R = in_sizes[1] / B;        // requests (8)
    const int D = in_sizes[4] / C;        // max path depth

    const int npairs = B * R;

    if (D == 16 && R == 8 && I == 512) {
        huff_lds16<<<B, 256, 0, stream>>>(x, tgt, W, bias, paths, codes, out);
    } else {
        const int grid = (npairs + WPB - 1) / WPB;
        huff_kernel_gen<<<grid, WPB * 64, 0, stream>>>(x, tgt, W, bias, paths, codes,
                                                       out, R, I, D, npairs);
    }
}

// Round 4
// 24.333 us; speedup vs baseline: 1.3600x; 1.3600x over previous
//
#include <hip/hip_runtime.h>
#include <math.h>

#define WPB 4   // waves per block

// ---- DPP wave reduction: VALU pipe only, no LDS/DS instructions ----
template<int CTRL, int ROW_MASK>
__device__ __forceinline__ float dpp_add(float v) {
    const int s = __builtin_amdgcn_update_dpp(0, __float_as_int(v),
                                              CTRL, ROW_MASK, 0xf, false);
    return v + __int_as_float(s);
}

// Full 64-lane sum; total lands in lane 63.
__device__ __forceinline__ float wave_sum63(float v) {
    v = dpp_add<0x111, 0xf>(v);  // row_shr:1
    v = dpp_add<0x112, 0xf>(v);  // row_shr:2
    v = dpp_add<0x114, 0xf>(v);  // row_shr:4
    v = dpp_add<0x118, 0xf>(v);  // row_shr:8  -> lane 16r+15 = row sum
    v = dpp_add<0x142, 0xa>(v);  // row_bcast:15 -> rows 1,3
    v = dpp_add<0x143, 0xc>(v);  // row_bcast:31 -> rows 2,3; lane 63 = total
    return v;
}

__device__ __forceinline__ float readlane_f(float v, int lane) {
    return __int_as_float(__builtin_amdgcn_readlane(__float_as_int(v), lane));
}

// One wave per (batch, request) pair. All D node ids known up-front ->
// all 2*D W-row loads issued with max MLP. D independent accumulators,
// D interleaved DPP reduction chains (VALU pipe), zero DS instructions.
// prod_d sigmoid(s_d*t_d) = 1 / prod_d (1 + exp(-s_d*t_d)), s_d = 1-2*code_d.
template<int D>
__global__ __launch_bounds__(WPB * 64, 4)
void huff_kernel(const float* __restrict__ x,     // (B, I)
                 const int*   __restrict__ tgt,   // (B, R)
                 const float* __restrict__ W,     // (N, I)
                 const float* __restrict__ bias,  // (N)
                 const int*   __restrict__ paths, // (C, D)
                 const float* __restrict__ codes, // (C, D)
                 float*       __restrict__ out,   // (B, R)
                 int R, int I, int npairs)
{
    const int lane = threadIdx.x & 63;
    const int p    = blockIdx.x * WPB + (threadIdx.x >> 6);
    if (p >= npairs) return;
    const int b = p / R;

    // x row: I == 512 -> two fully-coalesced 1KB wave loads
    const float4* xrow = reinterpret_cast<const float4*>(x + (size_t)b * I);
    const float4 xa = xrow[lane];
    const float4 xb = xrow[lane + 64];

    const int c  = tgt[p];
    const int dd = (lane < D) ? lane : (D - 1);
    const int   nd = paths[(size_t)c * D + dd];   // lane d holds path[d]
    const float cd = codes[(size_t)c * D + dd];
    const float sd = 1.0f - 2.0f * cd;            // sign
    const float bv = bias[nd];                    // lane d holds bias[path[d]]

    float acc[D];
    #pragma unroll
    for (int d = 0; d < D; ++d) {
        const int node = readlane_f(__int_as_float(nd), d) == 0.0f ? 0 : 0; (void)node;
        const int nid  = __builtin_amdgcn_readlane(nd, d);   // uniform node id
        const float4* wr = reinterpret_cast<const float4*>(W + (size_t)nid * I);
        const float4 wa = wr[lane];
        const float4 wb = wr[lane + 64];
        acc[d] = xa.x * wa.x + xa.y * wa.y + xa.z * wa.z + xa.w * wa.w
               + xb.x * wb.x + xb.y * wb.y + xb.z * wb.z + xb.w * wb.w;
    }

    // D interleaved 6-step DPP chains (VALU pipe)
    #pragma unroll
    for (int d = 0; d < D; ++d) acc[d] = wave_sum63(acc[d]);

    // uniform tail: q = prod(1 + exp(-s_d * t_d)); out = 1/q
    float q = 1.0f;
    #pragma unroll
    for (int d = 0; d < D; ++d) {
        const float tot = readlane_f(acc[d], 63);
        const float bb  = readlane_f(bv, d);
        const float ss  = readlane_f(sd, d);
        q *= 1.0f + __expf(-ss * (tot + bb));
    }
    if (lane == 0) out[p] = 1.0f / q;
}

// Generic fallback for unexpected shapes (shfl-based, correctness path).
__global__ __launch_bounds__(WPB * 64)
void huff_kernel_gen(const float* __restrict__ x, const int* __restrict__ tgt,
                     const float* __restrict__ W, const float* __restrict__ bias,
                     const int* __restrict__ paths, const float* __restrict__ codes,
                     float* __restrict__ out, int R, int I, int D, int npairs)
{
    const int lane = threadIdx.x & 63;
    const int p = blockIdx.x * WPB + (threadIdx.x >> 6);
    if (p >= npairs) return;
    const int b = p / R;
    const float4* xrow = reinterpret_cast<const float4*>(x + (size_t)b * I);
    const float4 xa = xrow[lane];
    const float4 xb = xrow[lane + 64];
    const int c = tgt[p];
    float q = 1.0f;
    for (int d = 0; d < D; ++d) {
        const int node = paths[(size_t)c * D + d];
        const float4* wr = reinterpret_cast<const float4*>(W + (size_t)node * I);
        const float4 wa = wr[lane];
        const float4 wb = wr[lane + 64];
        float acc = xa.x * wa.x + xa.y * wa.y + xa.z * wa.z + xa.w * wa.w
                  + xb.x * wb.x + xb.y * wb.y + xb.z * wb.z + xb.w * wb.w;
        #pragma unroll
        for (int off = 32; off; off >>= 1) acc += __shfl_xor(acc, off, 64);
        const float t = acc + bias[node];
        const float s = 1.0f - 2.0f * codes[(size_t)c * D + d];
        q *= 1.0f + __expf(-s * t);
    }
    if (lane == 0) out[p] = 1.0f / q;
}

extern "C" void kernel_launch(void* const* d_in, const int* in_sizes, int n_in,
                              void* d_out, int out_size, void* d_ws, size_t ws_size,
                              hipStream_t stream) {
    const float* x     = (const float*)d_in[0];
    const int*   tgt   = (const int*)  d_in[1];
    const float* W     = (const float*)d_in[2];
    const float* bias  = (const float*)d_in[3];
    const int*   paths = (const int*)  d_in[4];
    const float* codes = (const float*)d_in[5];
    float* out = (float*)d_out;

    const int N = in_sizes[3];            // total_nodes = nb_classes - 1
    const int C = N + 1;                  // nb_classes
    const int I = in_sizes[2] / N;        // input dim (512)
    const int B = in_sizes[0] / I;        // batch (1024)
    const int R = in_sizes[1] / B;        // requests (8)
    const int D = in_sizes[4] / C;        // max path depth

    const int npairs = B * R;
    const int grid = (npairs + WPB - 1) / WPB;

    switch (D) {
    case 15: huff_kernel<15><<<grid, WPB * 64, 0, stream>>>(x, tgt, W, bias, paths, codes, out, R, I, npairs); break;
    case 16: huff_kernel<16><<<grid, WPB * 64, 0, stream>>>(x, tgt, W, bias, paths, codes, out, R, I, npairs); break;
    case 17: huff_kernel<17><<<grid, WPB * 64, 0, stream>>>(x, tgt, W, bias, paths, codes, out, R, I, npairs); break;
    case 18: huff_kernel<18><<<grid, WPB * 64, 0, stream>>>(x, tgt, W, bias, paths, codes, out, R, I, npairs); break;
    default: huff_kernel_gen<<<grid, WPB * 64, 0, stream>>>(x, tgt, W, bias, paths, codes, out, R, I, D, npairs); break;
    }
}

// Round 5
// 24.119 us; speedup vs baseline: 1.3720x; 1.0088x over previous
//
#include <hip/hip_runtime.h>
#include <math.h>

// ---- DPP wave reduction: VALU pipe only, no LDS/DS instructions ----
template<int CTRL, int ROW_MASK>
__device__ __forceinline__ float dpp_add(float v) {
    const int s = __builtin_amdgcn_update_dpp(0, __float_as_int(v),
                                              CTRL, ROW_MASK, 0xf, false);
    return v + __int_as_float(s);
}

// Full 64-lane sum; total lands in lane 63.
__device__ __forceinline__ float wave_sum63(float v) {
    v = dpp_add<0x111, 0xf>(v);  // row_shr:1
    v = dpp_add<0x112, 0xf>(v);  // row_shr:2
    v = dpp_add<0x114, 0xf>(v);  // row_shr:4
    v = dpp_add<0x118, 0xf>(v);  // row_shr:8  -> lane 16r+15 = row sum
    v = dpp_add<0x142, 0xa>(v);  // row_bcast:15 -> rows 1,3
    v = dpp_add<0x143, 0xc>(v);  // row_bcast:31 -> lane 63 = total
    return v;
}

__device__ __forceinline__ float readlane_f(float v, int l) {
    return __int_as_float(__builtin_amdgcn_readlane(__float_as_int(v), l));
}

// Fast path (D==16, I==512, npairs even): TWO waves per (b,r) pair.
// Wave half h handles depths 8h..8h+7 -> only 8 W-row gathers per wave, so
// all 16 float4 load dests (~64 VGPR) fit in one fully-pipelined batch.
// Partial products combined through a 4-float LDS exchange.
__global__ __launch_bounds__(256, 4)
void huff_half(const float* __restrict__ x, const int* __restrict__ tgt,
               const float* __restrict__ W, const float* __restrict__ bias,
               const int* __restrict__ paths, const float* __restrict__ codes,
               float* __restrict__ out, int R, int I)
{
    __shared__ float qsh[2][2];
    const int lane = threadIdx.x & 63;
    const int w    = threadIdx.x >> 6;   // 0..3
    const int pi   = w >> 1;             // pair slot within block
    const int h    = w & 1;              // depth half
    const int p    = blockIdx.x * 2 + pi;
    const int b    = p / R;

    // x row: I == 512 -> two fully-coalesced 1KB wave loads
    const float4* xrow = reinterpret_cast<const float4*>(x + (size_t)b * I);
    const float4 xa = xrow[lane];
    const float4 xb = xrow[lane + 64];

    const int c     = tgt[p];
    const int dglob = h * 8 + (lane & 7);            // this wave's 8 depths
    const int   nd = paths[(size_t)c * 16 + dglob];  // lane d%8 holds path[]
    const float cd = codes[(size_t)c * 16 + dglob];
    const float sd = 1.0f - 2.0f * cd;               // sign
    const float bv = bias[nd];

    float acc[8];
    #pragma unroll
    for (int d = 0; d < 8; ++d) {
        const int nid = __builtin_amdgcn_readlane(nd, d);   // uniform node id
        const float4* wr = reinterpret_cast<const float4*>(W + (size_t)nid * I);
        const float4 wa = wr[lane];
        const float4 wb = wr[lane + 64];
        acc[d] = xa.x * wa.x + xa.y * wa.y + xa.z * wa.z + xa.w * wa.w
               + xb.x * wb.x + xb.y * wb.y + xb.z * wb.z + xb.w * wb.w;
    }

    // 8 interleaved 6-step DPP chains (VALU pipe)
    #pragma unroll
    for (int d = 0; d < 8; ++d) acc[d] = wave_sum63(acc[d]);

    // partial q over this wave's 8 depths
    float q = 1.0f;
    #pragma unroll
    for (int d = 0; d < 8; ++d) {
        const float tot = readlane_f(acc[d], 63);
        const float bb  = readlane_f(bv, d);
        const float ss  = readlane_f(sd, d);
        q *= 1.0f + __expf(-ss * (tot + bb));
    }
    if (lane == 0) qsh[pi][h] = q;
    __syncthreads();
    if (h == 0 && lane == 0) out[p] = 1.0f / (qsh[pi][0] * qsh[pi][1]);
}

// Generic fallback for unexpected shapes (shfl-based, correctness path).
__global__ __launch_bounds__(256)
void huff_kernel_gen(const float* __restrict__ x, const int* __restrict__ tgt,
                     const float* __restrict__ W, const float* __restrict__ bias,
                     const int* __restrict__ paths, const float* __restrict__ codes,
                     float* __restrict__ out, int R, int I, int D, int npairs)
{
    const int lane = threadIdx.x & 63;
    const int p = blockIdx.x * 4 + (threadIdx.x >> 6);
    if (p >= npairs) return;
    const int b = p / R;
    const float4* xrow = reinterpret_cast<const float4*>(x + (size_t)b * I);
    const float4 xa = xrow[lane];
    const float4 xb = xrow[lane + 64];
    const int c = tgt[p];
    float q = 1.0f;
    for (int d = 0; d < D; ++d) {
        const int node = paths[(size_t)c * D + d];
        const float4* wr = reinterpret_cast<const float4*>(W + (size_t)node * I);
        const float4 wa = wr[lane];
        const float4 wb = wr[lane + 64];
        float acc = xa.x * wa.x + xa.y * wa.y + xa.z * wa.z + xa.w * wa.w
                  + xb.x * wb.x + xb.y * wb.y + xb.z * wb.z + xb.w * wb.w;
        #pragma unroll
        for (int off = 32; off; off >>= 1) acc += __shfl_xor(acc, off, 64);
        const float t = acc + bias[node];
        const float s = 1.0f - 2.0f * codes[(size_t)c * D + d];
        q *= 1.0f + __expf(-s * t);
    }
    if (lane == 0) out[p] = 1.0f / q;
}

extern "C" void kernel_launch(void* const* d_in, const int* in_sizes, int n_in,
                              void* d_out, int out_size, void* d_ws, size_t ws_size,
                              hipStream_t stream) {
    const float* x     = (const float*)d_in[0];
    const int*   tgt   = (const int*)  d_in[1];
    const float* W     = (const float*)d_in[2];
    const float* bias  = (const float*)d_in[3];
    const int*   paths = (const int*)  d_in[4];
    const float* codes = (const float*)d_in[5];
    float* out = (float*)d_out;

    const int N = in_sizes[3];            // total_nodes = nb_classes - 1
    const int C = N + 1;                  // nb_classes
    const int I = in_sizes[2] / N;        // input dim (512)
    const int B = in_sizes[0] / I;        // batch (1024)
    const int R = in_sizes[1] / B;        // requests (8)
    const int D = in_sizes[4] / C;        // max path depth

    const int npairs = B * R;

    if (D == 16 && I == 512 && (npairs & 1) == 0) {
        // 2 waves per pair, 2 pairs per 256-thread block
        huff_half<<<npairs / 2, 256, 0, stream>>>(x, tgt, W, bias, paths, codes,
                                                  out, R, I);
    } else {
        const int grid = (npairs + 3) / 4;
        huff_kernel_gen<<<grid, 256, 0, stream>>>(x, tgt, W, bias, paths, codes,
                                                  out, R, I, D, npairs);
    }
}